// Round 13
// baseline (674.604 us; speedup 1.0000x reference)
//
#include <hip/hip_runtime.h>
#include <hip/hip_bf16.h>
#include <math.h>

// Problem constants (Encoder_24816321036413)
#define B_   16
#define L_   1024
#define BL_  16384      // B_*L_
#define DH_  512
#define DFF_ 2048
#define NL_  3
#define M_   8
#define DK_  64

typedef __attribute__((ext_vector_type(8))) short bf16x8;
typedef __attribute__((ext_vector_type(4))) float f32x4;
typedef __attribute__((ext_vector_type(16))) float f32x16;
typedef __attribute__((ext_vector_type(4))) unsigned short us4;
typedef __attribute__((ext_vector_type(8))) unsigned short us8;

__device__ __forceinline__ unsigned short f2b(float x) {
    __hip_bfloat16 h = __float2bfloat16(x);   // RNE
    return *(unsigned short*)&h;
}
__device__ __forceinline__ float b2f(unsigned short u) {
    unsigned int v = ((unsigned int)u) << 16;
    return __builtin_bit_cast(float, v);
}

#define GLDS(g, l) __builtin_amdgcn_global_load_lds( \
        (const __attribute__((address_space(1))) unsigned int*)(const void*)(g), \
        (__attribute__((address_space(3))) unsigned int*)(void*)(l), 16, 0, 0)

// ---------------------------------------------------------------------------
// One-shot weight prep (all layers): QKV fuse, Wo repack, FF0/FF1 cvt -> bf16
#define QKV_T 2359296   // 3 layers * 3 mats * 262144
#define WO_T  786432
#define FF_T  3145728   // 3 * 2048*512
__global__ __launch_bounds__(256) void wprep_kernel(
    const float* __restrict__ Wq, const float* __restrict__ Wk,
    const float* __restrict__ Wv, const float* __restrict__ Wo,
    const float* __restrict__ Wff0, const float* __restrict__ Wff1,
    unsigned short* __restrict__ wqkvb3, unsigned short* __restrict__ wob3,
    unsigned short* __restrict__ wff0b3, unsigned short* __restrict__ wff1b3)
{
    int i4 = (blockIdx.x * 256 + threadIdx.x) * 4;
    const float* src;
    unsigned short* dst;
    if (i4 < QKV_T) {
        int n = i4 / 786432, r = i4 % 786432;
        if (r < 262144)      src = Wq + (size_t)n * 262144 + r;
        else if (r < 524288) src = Wk + (size_t)n * 262144 + r - 262144;
        else                 src = Wv + (size_t)n * 262144 + r - 524288;
        dst = wqkvb3 + i4;
    } else if (i4 < QKV_T + WO_T) {
        int i = i4 - QKV_T;
        int n = i / 262144, r = i % 262144;
        int d = r >> 9, mv = r & 511, mm = mv >> 6, vv = mv & 63;
        src = Wo + (size_t)n * 262144 + ((size_t)mm * 512 + d) * 64 + vv;
        dst = wob3 + i;
    } else if (i4 < QKV_T + WO_T + FF_T) {
        int i = i4 - QKV_T - WO_T;
        src = Wff0 + i;
        dst = wff0b3 + i;
    } else {
        int i = i4 - QKV_T - WO_T - FF_T;
        src = Wff1 + i;
        dst = wff1b3 + i;
    }
    float4 v = *(const float4*)src;
    us4 o;
    o.x = f2b(v.x); o.y = f2b(v.y); o.z = f2b(v.z); o.w = f2b(v.w);
    *(us4*)dst = o;
}

// ---------------------------------------------------------------------------
__global__ __launch_bounds__(256) void embed_kernel(
    const float* __restrict__ x, const float* __restrict__ Wh,
    const float* __restrict__ bh, unsigned short* __restrict__ hb)
{
    int idx = blockIdx.x * 256 + threadIdx.x;   // BL_*DH_/4
    int bl = idx >> 7;
    int e0 = (idx & 127) * 4;
    float x0 = x[bl * 2], x1 = x[bl * 2 + 1];
    us4 o;
    #pragma unroll
    for (int r = 0; r < 4; ++r) {
        int e = e0 + r;
        float v = fmaf(x0, Wh[e * 2], fmaf(x1, Wh[e * 2 + 1], bh[e]));
        ((unsigned short*)&o)[r] = f2b(v);
    }
    *(us4*)&hb[(size_t)bl * DH_ + e0] = o;
}

// ---------------------------------------------------------------------------
// 2-WG/CU bf16 GEMM-NT (R10/R12 structure) with 32x32x16 MFMA microtile.
// BM=BN=128, BK=64; 512 thr = 8 waves (2M x 4N), per-wave 64x32 output =
// 2 x (32x32) tiles.  Per K-tile/wave: 8 MFMA @32k FLOP (was 16 @16k) --
// 32x32 matrix-pipe rate ~15% higher (m119) and half the issue slots.
// A/B frag: row/col = lane&31, k = (lane>>5)*8 + i (generalizes the proven
// 16x16x32 mapping).  C/D: col=lane&31, row=(reg&3)+8*(reg>>2)+4*(lane>>5)
// (guide-verified m74/m101).  LDS 2 slots x 32 KB = 64 KB -> 2 WG/CU;
// 1 barrier/K-tile, GLDS for k+1 issued at tile top.  T2 swizzle both-sides;
// T1 XCD swizzle.  flags: bit0 bias, bit1 relu, bit2 qkv-mode.
__global__ __launch_bounds__(512, 4) void gemm2w_kernel(
    const unsigned short* __restrict__ A, const unsigned short* __restrict__ Bm,
    const float* __restrict__ bias, unsigned short* __restrict__ Cb,
    unsigned short* __restrict__ vT, int K, int cn, int flags, int gx)
{
    constexpr int SLOT = 32768;                  // A 16K + B 16K
    __shared__ unsigned char lds[2 * SLOT];

    const int tid  = threadIdx.x;
    const int lane = tid & 63, wid = tid >> 6;
    const int wr = wid >> 2, wc = wid & 3;       // 2M x 4N waves
    const int l31 = lane & 31, ln5 = lane >> 5, l7 = lane & 7;

    const int nwg = gridDim.x;
    const int cpx = nwg >> 3;
    const int wg  = blockIdx.x;
    const int swz = (wg & 7) * cpx + (wg >> 3);
    const int by  = swz / gx;
    const int bx  = swz - by * gx;
    const int bm0 = by * 128, bn0 = bx * 128;

    const int srow  = tid >> 3;                  // 0..63
    const int scole = ((tid & 7) ^ (srow & 7)) * 8;   // pre-swizzled source col
    const unsigned short* Ag = A  + (size_t)(bm0 + srow) * K + scole;
    const unsigned short* Bg = Bm + (size_t)(bn0 + srow) * K + scole;

    f32x16 acc2[2];
    #pragma unroll
    for (int mb = 0; mb < 2; ++mb)
        #pragma unroll
        for (int i = 0; i < 16; ++i) acc2[mb][i] = 0.f;

    auto ldsA = [&](int slot, int sweep) -> void* {
        return (void*)(lds + slot * SLOT + sweep * 8192 + wid * 1024);
    };
    auto ldsB = [&](int slot, int sweep) -> void* {
        return (void*)(lds + slot * SLOT + 16384 + sweep * 8192 + wid * 1024);
    };
    auto srcA = [&](int kt, int sweep) {
        return Ag + (size_t)sweep * 64 * K + kt * 64;
    };
    auto srcB = [&](int kt, int sweep) {
        return Bg + (size_t)sweep * 64 * K + kt * 64;
    };

    const int nt = K >> 6;

    // Prologue: stage tile 0 -> slot 0
    GLDS(srcB(0, 0), ldsB(0, 0)); GLDS(srcB(0, 1), ldsB(0, 1));
    GLDS(srcA(0, 0), ldsA(0, 0)); GLDS(srcA(0, 1), ldsA(0, 1));
    asm volatile("s_waitcnt vmcnt(0)" ::: "memory");
    __builtin_amdgcn_s_barrier();

    for (int kt = 0; kt < nt; ++kt) {
        const int slot = kt & 1;
        const unsigned char* sb = lds + slot * SLOT;
        const int ns = slot ^ 1;
        const bool stg = (kt + 1 < nt);
        const int kn = kt + 1;

        if (stg) {   // issue first: maximum slack before the tile-end drain
            GLDS(srcB(kn, 0), ldsB(ns, 0)); GLDS(srcB(kn, 1), ldsB(ns, 1));
            GLDS(srcA(kn, 0), ldsA(ns, 0)); GLDS(srcA(kn, 1), ldsA(ns, 1));
        }
        // B frags (row = wc*32 + l31), reused by both m-blocks
        const unsigned char* bbase = sb + 16384 + (wc * 32 + l31) * 128;
        bf16x8 bfr[4];
        #pragma unroll
        for (int ks = 0; ks < 4; ++ks)
            bfr[ks] = *(const bf16x8*)(bbase + (((ks * 2 + ln5) ^ l7) << 4));
        #pragma unroll
        for (int mb = 0; mb < 2; ++mb) {
            const unsigned char* abase = sb + (wr * 64 + mb * 32 + l31) * 128;
            #pragma unroll
            for (int ks = 0; ks < 4; ++ks) {
                bf16x8 af = *(const bf16x8*)(abase + (((ks * 2 + ln5) ^ l7) << 4));
                acc2[mb] = __builtin_amdgcn_mfma_f32_32x32x16_bf16(
                    af, bfr[ks], acc2[mb], 0, 0, 0);
            }
        }
        if (stg) asm volatile("s_waitcnt vmcnt(0)" ::: "memory");
        __builtin_amdgcn_s_barrier();
    }

    // Epilogue.  C/D: col = lane&31, row = (reg&3) + 8*(reg>>2) + 4*(lane>>5).
    int col = bn0 + wc * 32 + l31;
    float bj = (flags & 1) ? bias[col] : 0.f;
    bool relu = flags & 2;
    bool qkvm = flags & 4;
    float qsc = (col < 512) ? 0.1803368801111244f : 1.0f;   // 0.125*log2e
    #pragma unroll
    for (int mb = 0; mb < 2; ++mb) {
        #pragma unroll
        for (int rq = 0; rq < 4; ++rq) {
            int row0 = bm0 + wr * 64 + mb * 32 + rq * 8 + ln5 * 4;
            float v[4];
            #pragma unroll
            for (int r = 0; r < 4; ++r) {
                v[r] = acc2[mb][rq * 4 + r] + bj;
                if (relu) v[r] = fmaxf(v[r], 0.f);
            }
            if (qkvm) {
                if (col < 1024) {          // q|k row-major; q pre-scaled for exp2
                    #pragma unroll
                    for (int r = 0; r < 4; ++r)
                        Cb[(size_t)(row0 + r) * cn + col] = f2b(v[r] * qsc);
                } else {                   // v -> vT[(b*8+m)*64+d][l]
                    int mm = (col - 1024) >> 6, dd = (col - 1024) & 63;
                    int bb = row0 >> 10, l0 = row0 & 1023;
                    us4 p;
                    p.x = f2b(v[0]); p.y = f2b(v[1]); p.z = f2b(v[2]); p.w = f2b(v[3]);
                    *(us4*)&vT[((size_t)(bb * 8 + mm) * 64 + dd) * 1024 + l0] = p;
                }
            } else {
                #pragma unroll
                for (int r = 0; r < 4; ++r)
                    Cb[(size_t)(row0 + r) * cn + col] = f2b(v[r]);
            }
        }
    }
}

// ---------------------------------------------------------------------------
// MFMA flash attention v3 (R11/R12, passing): operand-swapped QK/PV + XOR
// swizzle.  S^T = mfma(A=K, B=Q); P-writes b64; PV: O^T = mfma(A=V^T, B=P);
// per-lane lsum (2 shuffles); us4 output stores.  exp2f softmax.
__global__ __launch_bounds__(256, 4) void attn_mfma_kernel(
    const unsigned short* __restrict__ qk, const unsigned short* __restrict__ vT,
    unsigned short* __restrict__ t)
{
    __shared__ unsigned short Ks[64 * 64];     // [key][dh], swizzled rows
    __shared__ unsigned short Vs[64 * 64];     // [d][key],  swizzled rows
    __shared__ unsigned short Pb[4][32 * 64];  // per-wave [q][key], swizzled

    int tid = threadIdx.x;
    int lane = tid & 63, wid = tid >> 6;
    int fr = lane & 15, fq = lane >> 4;
    int j = blockIdx.x;
    int pair = (j & 7) * 16 + (j >> 6);        // 0..127 = b*8+m
    int q0 = ((j >> 3) & 7) * 128;
    int b = pair >> 3, m = pair & 7;
    int bq = b * L_;

    size_t qbase = (size_t)(bq + q0 + wid * 32) * 1024 + m * 64;
    bf16x8 qa[2][2];
    #pragma unroll
    for (int qh = 0; qh < 2; ++qh) {
        qa[qh][0] = *(const bf16x8*)&qk[qbase + (size_t)(qh * 16 + fr) * 1024 + fq * 8];
        qa[qh][1] = *(const bf16x8*)&qk[qbase + (size_t)(qh * 16 + fr) * 1024 + 32 + fq * 8];
    }

    f32x4 oaccT[2][4];                         // [qh][nt] : O^T[d][q]
    #pragma unroll
    for (int qh = 0; qh < 2; ++qh)
        #pragma unroll
        for (int i = 0; i < 4; ++i) oaccT[qh][i] = (f32x4){0.f, 0.f, 0.f, 0.f};
    float lsum[2] = {0.f, 0.f};                // per-lane: q = qh*16+fr

    int srow = tid >> 3;                       // 0..31 (and +32)
    int c16  = tid & 7;                        // 16B chunk within 128B row
    int scole = (c16 ^ (srow & 7)) * 8;        // pre-swizzled source col (elems)
    const unsigned short* kg = qk + (size_t)bq * 1024 + 512 + m * 64 + scole;
    const unsigned short* vg = vT + ((size_t)pair * 64) * 1024 + scole;
    unsigned short* pw = Pb[wid];
    const int u7 = fr & 7;

    uint4 k0 = *(const uint4*)&kg[(size_t)(srow) * 1024];
    uint4 k1 = *(const uint4*)&kg[(size_t)(srow + 32) * 1024];
    uint4 v0 = *(const uint4*)&vg[(size_t)(srow) * 1024];
    uint4 v1 = *(const uint4*)&vg[(size_t)(srow + 32) * 1024];

    for (int kt = 0; kt < L_ / 64; ++kt) {
        __syncthreads();
        *(uint4*)&Ks[(srow)      * 64 + c16 * 8] = k0;
        *(uint4*)&Ks[(srow + 32) * 64 + c16 * 8] = k1;
        *(uint4*)&Vs[(srow)      * 64 + c16 * 8] = v0;
        *(uint4*)&Vs[(srow + 32) * 64 + c16 * 8] = v1;
        __syncthreads();
        if (kt + 1 < L_ / 64) {
            int kb = (kt + 1) * 64;
            k0 = *(const uint4*)&kg[(size_t)(kb + srow) * 1024];
            k1 = *(const uint4*)&kg[(size_t)(kb + srow + 32) * 1024];
            v0 = *(const uint4*)&vg[(size_t)(srow) * 1024 + kb];
            v1 = *(const uint4*)&vg[(size_t)(srow + 32) * 1024 + kb];
        }

        __builtin_amdgcn_s_setprio(1);
        #pragma unroll
        for (int nk = 0; nk < 4; ++nk) {
            const unsigned short* krow = &Ks[(nk * 16 + fr) * 64];
            bf16x8 kf0 = *(const bf16x8*)&krow[((fq     ) ^ u7) * 8];
            bf16x8 kf1 = *(const bf16x8*)&krow[((4 + fq) ^ u7) * 8];
            #pragma unroll
            for (int qh = 0; qh < 2; ++qh) {
                f32x4 s = __builtin_amdgcn_mfma_f32_16x16x32_bf16(
                    kf0, qa[qh][0], (f32x4){0.f, 0.f, 0.f, 0.f}, 0, 0, 0);
                s = __builtin_amdgcn_mfma_f32_16x16x32_bf16(kf1, qa[qh][1], s, 0, 0, 0);
                us4 pk;
                #pragma unroll
                for (int r = 0; r < 4; ++r) {
                    float p = exp2f(s[r]);
                    lsum[qh] += p;
                    ((unsigned short*)&pk)[r] = f2b(p);
                }
                int prow = qh * 16 + fr;
                int pc16 = nk * 2 + (fq >> 1);
                int addr = prow * 128 + ((pc16 ^ (prow & 7)) << 4) + (fq & 1) * 8;
                *(us4*)((unsigned char*)pw + addr) = pk;
            }
        }
        bf16x8 pa[2][2];
        #pragma unroll
        for (int qh = 0; qh < 2; ++qh) {
            int prow = qh * 16 + fr;
            const unsigned char* pr = (const unsigned char*)pw + prow * 128;
            pa[qh][0] = *(const bf16x8*)(pr + (((fq    ) ^ (prow & 7)) << 4));
            pa[qh][1] = *(const bf16x8*)(pr + (((4 + fq) ^ (prow & 7)) << 4));
        }
        #pragma unroll
        for (int nt = 0; nt < 4; ++nt) {
            const unsigned short* vrow = &Vs[(nt * 16 + fr) * 64];
            bf16x8 vf0 = *(const bf16x8*)&vrow[((fq     ) ^ u7) * 8];
            bf16x8 vf1 = *(const bf16x8*)&vrow[((4 + fq) ^ u7) * 8];
            #pragma unroll
            for (int qh = 0; qh < 2; ++qh) {
                oaccT[qh][nt] = __builtin_amdgcn_mfma_f32_16x16x32_bf16(
                    vf0, pa[qh][0], oaccT[qh][nt], 0, 0, 0);
                oaccT[qh][nt] = __builtin_amdgcn_mfma_f32_16x16x32_bf16(
                    vf1, pa[qh][1], oaccT[qh][nt], 0, 0, 0);
            }
        }
        __builtin_amdgcn_s_setprio(0);
    }

    float inv[2];
    #pragma unroll
    for (int qh = 0; qh < 2; ++qh) {
        float s = lsum[qh];
        s += __shfl_xor(s, 16);
        s += __shfl_xor(s, 32);
        inv[qh] = 1.f / s;
    }
    #pragma unroll
    for (int qh = 0; qh < 2; ++qh) {
        size_t orow = (size_t)(bq + q0 + wid * 32 + qh * 16 + fr) * DH_ + m * 64;
        #pragma unroll
        for (int nt = 0; nt < 4; ++nt) {
            us4 ob;
            #pragma unroll
            for (int r = 0; r < 4; ++r)
                ((unsigned short*)&ob)[r] = f2b(oaccT[qh][nt][r] * inv[qh]);
            *(us4*)&t[orow + nt * 16 + fq * 4] = ob;
        }
    }
}

// ---------------------------------------------------------------------------
// Fused BatchNorm: one block per position l, z = a+b cached in registers.
// Stats use the EXACT reduce order of the old bn_stats (bitwise-identical),
// then apply from registers.  48 MB/pair vs 80 MB for the split version.
__global__ __launch_bounds__(256) void bn_fused_kernel(
    const unsigned short* __restrict__ a, const unsigned short* __restrict__ b,
    const float* __restrict__ w, const float* __restrict__ bias,
    unsigned short* __restrict__ outb, float* __restrict__ outf)
{
    int l = blockIdx.x, tid = threadIdx.x;
    us8 za[4], zb[4];
    size_t offs[4];
    float s = 0.f, s2 = 0.f;
    #pragma unroll
    for (int i = 0; i < 4; ++i) {
        int u = tid + i * 256;
        int bb = u >> 6, dg = (u & 63) * 8;
        size_t off = ((size_t)bb * L_ + l) * DH_ + dg;
        offs[i] = off;
        za[i] = *(const us8*)&a[off];
        zb[i] = *(const us8*)&b[off];
        #pragma unroll
        for (int jj = 0; jj < 8; ++jj) {
            float z = b2f(za[i][jj]) + b2f(zb[i][jj]);
            s += z;
            s2 = fmaf(z, z, s2);
        }
    }
    #pragma unroll
    for (int off = 32; off > 0; off >>= 1) {
        s  += __shfl_down(s, off);
        s2 += __shfl_down(s2, off);
    }
    __shared__ float red[8];
    __shared__ float mrs[2];
    int wv = tid >> 6;
    if ((tid & 63) == 0) { red[wv] = s; red[4 + wv] = s2; }
    __syncthreads();
    if (tid == 0) {
        float S  = red[0] + red[1] + red[2] + red[3];
        float S2 = red[4] + red[5] + red[6] + red[7];
        float mu  = S * (1.f / 8192.f);
        float var = S2 * (1.f / 8192.f) - mu * mu;
        mrs[0] = mu;
        mrs[1] = rsqrtf(var + 1e-5f);
    }
    __syncthreads();
    float mu = mrs[0], rs = mrs[1];
    #pragma unroll
    for (int i = 0; i < 4; ++i) {
        int u = tid + i * 256;
        int dg = (u & 63) * 8;
        float o[8];
        #pragma unroll
        for (int jj = 0; jj < 8; ++jj) {
            float z = b2f(za[i][jj]) + b2f(zb[i][jj]);
            o[jj] = fmaf(w[dg + jj], (z - mu) * rs, bias[dg + jj]);
        }
        if (outb) {
            us8 ob;
            #pragma unroll
            for (int jj = 0; jj < 8; ++jj) ob[jj] = f2b(o[jj]);
            *(us8*)&outb[offs[i]] = ob;
        }
        if (outf) {
            float4 o0 = {o[0], o[1], o[2], o[3]};
            float4 o1 = {o[4], o[5], o[6], o[7]};
            *(float4*)&outf[offs[i]]     = o0;
            *(float4*)&outf[offs[i] + 4] = o1;
        }
    }
}

// ---------------------------------------------------------------------------
extern "C" void kernel_launch(void* const* d_in, const int* in_sizes, int n_in,
                              void* d_out, int out_size, void* d_ws, size_t ws_size,
                              hipStream_t stream)
{
    const float* x    = (const float*)d_in[0];
    const float* Wh   = (const float*)d_in[1];
    const float* bh   = (const float*)d_in[2];
    const float* Wq   = (const float*)d_in[3];
    const float* Wk   = (const float*)d_in[4];
    const float* Wv   = (const float*)d_in[5];
    const float* Wo   = (const float*)d_in[6];
    const float* wbn  = (const float*)d_in[7];
    const float* bbn  = (const float*)d_in[8];
    const float* Wff0 = (const float*)d_in[9];
    const float* bff0 = (const float*)d_in[10];
    const float* Wff1 = (const float*)d_in[11];
    const float* bff1 = (const float*)d_in[12];
    float* out = (float*)d_out;

    // Workspace (~146 MB), all activations bf16 (layout as R5-R12; st kept
    // for layout stability though unused by the fused BN)
    float* st = (float*)d_ws;
    unsigned short* hb    = (unsigned short*)(st + 2048);
    unsigned short* qkkb  = hb + (size_t)BL_ * DH_;
    unsigned short* vTb   = qkkb + (size_t)BL_ * 1024;
    unsigned short* tb    = vTb + (size_t)BL_ * DH_;
    unsigned short* mhab  = tb + (size_t)BL_ * DH_;
    unsigned short* hbnb  = mhab + (size_t)BL_ * DH_;
    unsigned short* ffob  = hbnb + (size_t)BL_ * DH_;
    unsigned short* wqkvb3 = ffob + (size_t)BL_ * DH_;
    unsigned short* wob3   = wqkvb3 + QKV_T;
    unsigned short* wff0b3 = wob3 + WO_T;
    unsigned short* wff1b3 = wff0b3 + FF_T;
    unsigned short* ffmb  = qkkb;    // alias (qkkb+vTb+tb = 64MB, dead at FF)

    wprep_kernel<<<(QKV_T + WO_T + 2 * FF_T) / 1024, 256, 0, stream>>>(
        Wq, Wk, Wv, Wo, Wff0, Wff1, wqkvb3, wob3, wff0b3, wff1b3);
    embed_kernel<<<BL_ * DH_ / 4 / 256, 256, 0, stream>>>(x, Wh, bh, hb);

    // 1D grids (%8 for XCD swizzle), tile 128x128
    const int GQKV = 12 * 128;   // gx=12
    const int GWO  = 4 * 128;    // gx=4
    const int GFF0 = 16 * 128;   // gx=16
    const int GFF1 = 4 * 128;    // gx=4

    for (int n = 0; n < NL_; ++n) {
        const unsigned short* wqkvb = wqkvb3 + (size_t)n * 786432;
        const unsigned short* wob   = wob3   + (size_t)n * 262144;
        const unsigned short* wff0b = wff0b3 + (size_t)n * 1048576;
        const unsigned short* wff1b = wff1b3 + (size_t)n * 1048576;
        const float* wbn_n  = wbn  + (size_t)n * DH_;
        const float* bbn_n  = bbn  + (size_t)n * DH_;
        const float* bff0_n = bff0 + (size_t)n * DFF_;
        const float* bff1_n = bff1 + (size_t)n * DH_;
        bool last = (n == NL_ - 1);

        // qkv: q|k -> qkkb [BL][1024] (q pre-scaled), v -> vTb transposed
        gemm2w_kernel<<<GQKV, 512, 0, stream>>>(hb, wqkvb, nullptr,
            qkkb, vTb, DH_, 1024, 4, 12);
        // t = softmax(q k^T / 8) v -> tb
        attn_mfma_kernel<<<1024, 256, 0, stream>>>(qkkb, vTb, tb);
        // h_mha = t @ wob^T -> mhab
        gemm2w_kernel<<<GWO, 512, 0, stream>>>(tb, wob, nullptr,
            mhab, nullptr, DH_, DH_, 0, 4);
        // h_bn = w*BN(h + h_mha) + b -> hbnb   (fused stats+apply)
        bn_fused_kernel<<<L_, 256, 0, stream>>>(hb, mhab, wbn_n, bbn_n,
            hbnb, nullptr);
        // ff = relu(h_bn @ Wff0^T + bff0) @ Wff1^T + bff1 -> ffob
        gemm2w_kernel<<<GFF0, 512, 0, stream>>>(hbnb, wff0b, bff0_n,
            ffmb, nullptr, DH_, DFF_, 1 | 2, 16);
        gemm2w_kernel<<<GFF1, 512, 0, stream>>>(ffmb, wff1b, bff1_n,
            ffob, nullptr, DFF_, DH_, 1, 4);
        // h = w*BN(h_bn + ff) + b  (final layer -> fp32 d_out)
        bn_fused_kernel<<<L_, 256, 0, stream>>>(hbnb, ffob, wbn_n, bbn_n,
            last ? nullptr : hb, last ? out : nullptr);
    }
}

// Round 14
// 625.945 us; speedup vs baseline: 1.0777x; 1.0777x over previous
//
#include <hip/hip_runtime.h>
#include <hip/hip_bf16.h>
#include <math.h>

// Problem constants (Encoder_24816321036413)
#define B_   16
#define L_   1024
#define BL_  16384      // B_*L_
#define DH_  512
#define DFF_ 2048
#define NL_  3
#define M_   8
#define DK_  64

typedef __attribute__((ext_vector_type(8))) short bf16x8;
typedef __attribute__((ext_vector_type(4))) float f32x4;
typedef __attribute__((ext_vector_type(4))) unsigned short us4;
typedef __attribute__((ext_vector_type(8))) unsigned short us8;

__device__ __forceinline__ unsigned short f2b(float x) {
    __hip_bfloat16 h = __float2bfloat16(x);   // RNE
    return *(unsigned short*)&h;
}
__device__ __forceinline__ float b2f(unsigned short u) {
    unsigned int v = ((unsigned int)u) << 16;
    return __builtin_bit_cast(float, v);
}

#define GLDS(g, l) __builtin_amdgcn_global_load_lds( \
        (const __attribute__((address_space(1))) unsigned int*)(const void*)(g), \
        (__attribute__((address_space(3))) unsigned int*)(void*)(l), 16, 0, 0)

// ---------------------------------------------------------------------------
// One-shot weight prep (all layers): QKV fuse, Wo repack, FF0/FF1 cvt -> bf16
#define QKV_T 2359296   // 3 layers * 3 mats * 262144
#define WO_T  786432
#define FF_T  3145728   // 3 * 2048*512
__global__ __launch_bounds__(256) void wprep_kernel(
    const float* __restrict__ Wq, const float* __restrict__ Wk,
    const float* __restrict__ Wv, const float* __restrict__ Wo,
    const float* __restrict__ Wff0, const float* __restrict__ Wff1,
    unsigned short* __restrict__ wqkvb3, unsigned short* __restrict__ wob3,
    unsigned short* __restrict__ wff0b3, unsigned short* __restrict__ wff1b3)
{
    int i4 = (blockIdx.x * 256 + threadIdx.x) * 4;
    const float* src;
    unsigned short* dst;
    if (i4 < QKV_T) {
        int n = i4 / 786432, r = i4 % 786432;
        if (r < 262144)      src = Wq + (size_t)n * 262144 + r;
        else if (r < 524288) src = Wk + (size_t)n * 262144 + r - 262144;
        else                 src = Wv + (size_t)n * 262144 + r - 524288;
        dst = wqkvb3 + i4;
    } else if (i4 < QKV_T + WO_T) {
        int i = i4 - QKV_T;
        int n = i / 262144, r = i % 262144;
        int d = r >> 9, mv = r & 511, mm = mv >> 6, vv = mv & 63;
        src = Wo + (size_t)n * 262144 + ((size_t)mm * 512 + d) * 64 + vv;
        dst = wob3 + i;
    } else if (i4 < QKV_T + WO_T + FF_T) {
        int i = i4 - QKV_T - WO_T;
        src = Wff0 + i;
        dst = wff0b3 + i;
    } else {
        int i = i4 - QKV_T - WO_T - FF_T;
        src = Wff1 + i;
        dst = wff1b3 + i;
    }
    float4 v = *(const float4*)src;
    us4 o;
    o.x = f2b(v.x); o.y = f2b(v.y); o.z = f2b(v.z); o.w = f2b(v.w);
    *(us4*)dst = o;
}

// ---------------------------------------------------------------------------
__global__ __launch_bounds__(256) void embed_kernel(
    const float* __restrict__ x, const float* __restrict__ Wh,
    const float* __restrict__ bh, unsigned short* __restrict__ hb)
{
    int idx = blockIdx.x * 256 + threadIdx.x;   // BL_*DH_/4
    int bl = idx >> 7;
    int e0 = (idx & 127) * 4;
    float x0 = x[bl * 2], x1 = x[bl * 2 + 1];
    us4 o;
    #pragma unroll
    for (int r = 0; r < 4; ++r) {
        int e = e0 + r;
        float v = fmaf(x0, Wh[e * 2], fmaf(x1, Wh[e * 2 + 1], bh[e]));
        ((unsigned short*)&o)[r] = f2b(v);
    }
    *(us4*)&hb[(size_t)bl * DH_ + e0] = o;
}

// ---------------------------------------------------------------------------
// 2-WG/CU bf16 GEMM-NT (R10/R12 structure, 16x16x32 MFMA — proven fastest;
// R13's 32x32x16 variant REGRESSED: 2x4-deep serial acc chains killed ILP).
// BM=BN=128, BK=64; 512 thr = 8 waves (2M x 4N), per-wave 64x32 output.
// LDS = 2 slots x 32 KB = 64 KB -> 2 WG/CU; 1 barrier/K-tile; GLDS for k+1
// issued at tile top.  T2 swizzle both-sides; T1 XCD swizzle on 1D grid.
// flags: bit0 bias, bit1 relu, bit2 qkv-mode (col<1024 -> Cb stride cn with
//        q-cols (<512) pre-scaled by 0.125*log2e; col>=1024 -> vT scatter).
__global__ __launch_bounds__(512, 4) void gemm2w_kernel(
    const unsigned short* __restrict__ A, const unsigned short* __restrict__ Bm,
    const float* __restrict__ bias, unsigned short* __restrict__ Cb,
    unsigned short* __restrict__ vT, int K, int cn, int flags, int gx)
{
    constexpr int SLOT = 32768;                  // A 16K + B 16K
    __shared__ unsigned char lds[2 * SLOT];

    const int tid  = threadIdx.x;
    const int lane = tid & 63, wid = tid >> 6;
    const int wr = wid >> 2, wc = wid & 3;       // 2M x 4N waves
    const int fr = lane & 15, fq = lane >> 4;

    const int nwg = gridDim.x;
    const int cpx = nwg >> 3;
    const int wg  = blockIdx.x;
    const int swz = (wg & 7) * cpx + (wg >> 3);
    const int by  = swz / gx;
    const int bx  = swz - by * gx;
    const int bm0 = by * 128, bn0 = bx * 128;
    const int cxor = (fr & 7) << 4;              // read-side swizzle XOR (bytes)

    const int srow  = tid >> 3;                  // 0..63
    const int scole = ((tid & 7) ^ (srow & 7)) * 8;   // pre-swizzled source col
    const unsigned short* Ag = A  + (size_t)(bm0 + srow) * K + scole;
    const unsigned short* Bg = Bm + (size_t)(bn0 + srow) * K + scole;

    f32x4 acc[4][2];
    #pragma unroll
    for (int i = 0; i < 4; ++i)
        #pragma unroll
        for (int j = 0; j < 2; ++j)
            acc[i][j] = (f32x4){0.f, 0.f, 0.f, 0.f};

    auto ldsA = [&](int slot, int sweep) -> void* {
        return (void*)(lds + slot * SLOT + sweep * 8192 + wid * 1024);
    };
    auto ldsB = [&](int slot, int sweep) -> void* {
        return (void*)(lds + slot * SLOT + 16384 + sweep * 8192 + wid * 1024);
    };
    auto srcA = [&](int kt, int sweep) {
        return Ag + (size_t)sweep * 64 * K + kt * 64;
    };
    auto srcB = [&](int kt, int sweep) {
        return Bg + (size_t)sweep * 64 * K + kt * 64;
    };

    const int nt = K >> 6;

    // Prologue: stage tile 0 -> slot 0
    GLDS(srcB(0, 0), ldsB(0, 0)); GLDS(srcB(0, 1), ldsB(0, 1));
    GLDS(srcA(0, 0), ldsA(0, 0)); GLDS(srcA(0, 1), ldsA(0, 1));
    asm volatile("s_waitcnt vmcnt(0)" ::: "memory");
    __builtin_amdgcn_s_barrier();

    for (int kt = 0; kt < nt; ++kt) {
        const int slot = kt & 1;
        const unsigned char* sb = lds + slot * SLOT;
        const int ns = slot ^ 1;
        const bool stg = (kt + 1 < nt);
        const int kn = kt + 1;

        if (stg) {   // issue first: maximum slack before the tile-end drain
            GLDS(srcB(kn, 0), ldsB(ns, 0)); GLDS(srcB(kn, 1), ldsB(ns, 1));
            GLDS(srcA(kn, 0), ldsA(ns, 0)); GLDS(srcA(kn, 1), ldsA(ns, 1));
        }
        // B-frags: read once per tile, reused across both m-halves
        bf16x8 bfr[2][2], af[2][2];
        #pragma unroll
        for (int ni = 0; ni < 2; ++ni)
            #pragma unroll
            for (int kk = 0; kk < 2; ++kk)
                bfr[ni][kk] = *(const bf16x8*)(sb + 16384 +
                    (wc * 32 + ni * 16 + fr) * 128 + ((kk * 64 + fq * 16) ^ cxor));
        #pragma unroll
        for (int mi = 0; mi < 2; ++mi)
            #pragma unroll
            for (int kk = 0; kk < 2; ++kk)
                af[mi][kk] = *(const bf16x8*)(sb +
                    (wr * 64 + mi * 16 + fr) * 128 + ((kk * 64 + fq * 16) ^ cxor));
        #pragma unroll
        for (int mi = 0; mi < 2; ++mi)
            #pragma unroll
            for (int ni = 0; ni < 2; ++ni) {
                f32x4 c = acc[mi][ni];
                c = __builtin_amdgcn_mfma_f32_16x16x32_bf16(af[mi][0], bfr[ni][0], c, 0, 0, 0);
                c = __builtin_amdgcn_mfma_f32_16x16x32_bf16(af[mi][1], bfr[ni][1], c, 0, 0, 0);
                acc[mi][ni] = c;
            }
        // m-half 1
        #pragma unroll
        for (int mi = 0; mi < 2; ++mi)
            #pragma unroll
            for (int kk = 0; kk < 2; ++kk)
                af[mi][kk] = *(const bf16x8*)(sb +
                    (wr * 64 + 32 + mi * 16 + fr) * 128 + ((kk * 64 + fq * 16) ^ cxor));
        #pragma unroll
        for (int mi = 0; mi < 2; ++mi)
            #pragma unroll
            for (int ni = 0; ni < 2; ++ni) {
                f32x4 c = acc[2 + mi][ni];
                c = __builtin_amdgcn_mfma_f32_16x16x32_bf16(af[mi][0], bfr[ni][0], c, 0, 0, 0);
                c = __builtin_amdgcn_mfma_f32_16x16x32_bf16(af[mi][1], bfr[ni][1], c, 0, 0, 0);
                acc[2 + mi][ni] = c;
            }
        if (stg) asm volatile("s_waitcnt vmcnt(0)" ::: "memory");
        __builtin_amdgcn_s_barrier();
    }

    // Epilogue
    float bj[2] = {0.f, 0.f};
    if (flags & 1) {
        #pragma unroll
        for (int ni = 0; ni < 2; ++ni)
            bj[ni] = bias[bn0 + wc * 32 + ni * 16 + fr];
    }
    bool relu = flags & 2;
    bool qkvm = flags & 4;
    #pragma unroll
    for (int am = 0; am < 4; ++am) {
        int row0 = bm0 + wr * 64 + (am >> 1) * 32 + (am & 1) * 16 + fq * 4;
        #pragma unroll
        for (int an = 0; an < 2; ++an) {
            int col = bn0 + wc * 32 + an * 16 + fr;
            float v[4];
            #pragma unroll
            for (int r = 0; r < 4; ++r) {
                v[r] = acc[am][an][r] + bj[an];
                if (relu) v[r] = fmaxf(v[r], 0.f);
            }
            if (qkvm) {
                if (col < 1024) {          // q|k row-major; q pre-scaled for exp2
                    float sc = (col < 512) ? 0.1803368801111244f : 1.0f;
                    #pragma unroll
                    for (int r = 0; r < 4; ++r)
                        Cb[(size_t)(row0 + r) * cn + col] = f2b(v[r] * sc);
                } else {                   // v -> vT[(b*8+m)*64+d][l]
                    int mm = (col - 1024) >> 6, dd = (col - 1024) & 63;
                    int bb = row0 >> 10, l0 = row0 & 1023;
                    us4 p;
                    p.x = f2b(v[0]); p.y = f2b(v[1]); p.z = f2b(v[2]); p.w = f2b(v[3]);
                    *(us4*)&vT[((size_t)(bb * 8 + mm) * 64 + dd) * 1024 + l0] = p;
                }
            } else {
                #pragma unroll
                for (int r = 0; r < 4; ++r)
                    Cb[(size_t)(row0 + r) * cn + col] = f2b(v[r]);
            }
        }
    }
}

// ---------------------------------------------------------------------------
// MFMA flash attention v3 (R11/R12, passing): operand-swapped QK/PV + XOR
// swizzle.  S^T = mfma(A=K, B=Q); P-writes b64; PV: O^T = mfma(A=V^T, B=P);
// per-lane lsum (2 shuffles); us4 output stores.  exp2f softmax.
__global__ __launch_bounds__(256, 4) void attn_mfma_kernel(
    const unsigned short* __restrict__ qk, const unsigned short* __restrict__ vT,
    unsigned short* __restrict__ t)
{
    __shared__ unsigned short Ks[64 * 64];     // [key][dh], swizzled rows
    __shared__ unsigned short Vs[64 * 64];     // [d][key],  swizzled rows
    __shared__ unsigned short Pb[4][32 * 64];  // per-wave [q][key], swizzled

    int tid = threadIdx.x;
    int lane = tid & 63, wid = tid >> 6;
    int fr = lane & 15, fq = lane >> 4;
    int j = blockIdx.x;
    int pair = (j & 7) * 16 + (j >> 6);        // 0..127 = b*8+m
    int q0 = ((j >> 3) & 7) * 128;
    int b = pair >> 3, m = pair & 7;
    int bq = b * L_;

    size_t qbase = (size_t)(bq + q0 + wid * 32) * 1024 + m * 64;
    bf16x8 qa[2][2];
    #pragma unroll
    for (int qh = 0; qh < 2; ++qh) {
        qa[qh][0] = *(const bf16x8*)&qk[qbase + (size_t)(qh * 16 + fr) * 1024 + fq * 8];
        qa[qh][1] = *(const bf16x8*)&qk[qbase + (size_t)(qh * 16 + fr) * 1024 + 32 + fq * 8];
    }

    f32x4 oaccT[2][4];                         // [qh][nt] : O^T[d][q]
    #pragma unroll
    for (int qh = 0; qh < 2; ++qh)
        #pragma unroll
        for (int i = 0; i < 4; ++i) oaccT[qh][i] = (f32x4){0.f, 0.f, 0.f, 0.f};
    float lsum[2] = {0.f, 0.f};                // per-lane: q = qh*16+fr

    int srow = tid >> 3;                       // 0..31 (and +32)
    int c16  = tid & 7;                        // 16B chunk within 128B row
    int scole = (c16 ^ (srow & 7)) * 8;        // pre-swizzled source col (elems)
    const unsigned short* kg = qk + (size_t)bq * 1024 + 512 + m * 64 + scole;
    const unsigned short* vg = vT + ((size_t)pair * 64) * 1024 + scole;
    unsigned short* pw = Pb[wid];
    const int u7 = fr & 7;

    uint4 k0 = *(const uint4*)&kg[(size_t)(srow) * 1024];
    uint4 k1 = *(const uint4*)&kg[(size_t)(srow + 32) * 1024];
    uint4 v0 = *(const uint4*)&vg[(size_t)(srow) * 1024];
    uint4 v1 = *(const uint4*)&vg[(size_t)(srow + 32) * 1024];

    for (int kt = 0; kt < L_ / 64; ++kt) {
        __syncthreads();
        *(uint4*)&Ks[(srow)      * 64 + c16 * 8] = k0;
        *(uint4*)&Ks[(srow + 32) * 64 + c16 * 8] = k1;
        *(uint4*)&Vs[(srow)      * 64 + c16 * 8] = v0;
        *(uint4*)&Vs[(srow + 32) * 64 + c16 * 8] = v1;
        __syncthreads();
        if (kt + 1 < L_ / 64) {
            int kb = (kt + 1) * 64;
            k0 = *(const uint4*)&kg[(size_t)(kb + srow) * 1024];
            k1 = *(const uint4*)&kg[(size_t)(kb + srow + 32) * 1024];
            v0 = *(const uint4*)&vg[(size_t)(srow) * 1024 + kb];
            v1 = *(const uint4*)&vg[(size_t)(srow + 32) * 1024 + kb];
        }

        __builtin_amdgcn_s_setprio(1);
        #pragma unroll
        for (int nk = 0; nk < 4; ++nk) {
            const unsigned short* krow = &Ks[(nk * 16 + fr) * 64];
            bf16x8 kf0 = *(const bf16x8*)&krow[((fq     ) ^ u7) * 8];
            bf16x8 kf1 = *(const bf16x8*)&krow[((4 + fq) ^ u7) * 8];
            #pragma unroll
            for (int qh = 0; qh < 2; ++qh) {
                f32x4 s = __builtin_amdgcn_mfma_f32_16x16x32_bf16(
                    kf0, qa[qh][0], (f32x4){0.f, 0.f, 0.f, 0.f}, 0, 0, 0);
                s = __builtin_amdgcn_mfma_f32_16x16x32_bf16(kf1, qa[qh][1], s, 0, 0, 0);
                us4 pk;
                #pragma unroll
                for (int r = 0; r < 4; ++r) {
                    float p = exp2f(s[r]);
                    lsum[qh] += p;
                    ((unsigned short*)&pk)[r] = f2b(p);
                }
                int prow = qh * 16 + fr;
                int pc16 = nk * 2 + (fq >> 1);
                int addr = prow * 128 + ((pc16 ^ (prow & 7)) << 4) + (fq & 1) * 8;
                *(us4*)((unsigned char*)pw + addr) = pk;
            }
        }
        bf16x8 pa[2][2];
        #pragma unroll
        for (int qh = 0; qh < 2; ++qh) {
            int prow = qh * 16 + fr;
            const unsigned char* pr = (const unsigned char*)pw + prow * 128;
            pa[qh][0] = *(const bf16x8*)(pr + (((fq    ) ^ (prow & 7)) << 4));
            pa[qh][1] = *(const bf16x8*)(pr + (((4 + fq) ^ (prow & 7)) << 4));
        }
        #pragma unroll
        for (int nt = 0; nt < 4; ++nt) {
            const unsigned short* vrow = &Vs[(nt * 16 + fr) * 64];
            bf16x8 vf0 = *(const bf16x8*)&vrow[((fq     ) ^ u7) * 8];
            bf16x8 vf1 = *(const bf16x8*)&vrow[((4 + fq) ^ u7) * 8];
            #pragma unroll
            for (int qh = 0; qh < 2; ++qh) {
                oaccT[qh][nt] = __builtin_amdgcn_mfma_f32_16x16x32_bf16(
                    vf0, pa[qh][0], oaccT[qh][nt], 0, 0, 0);
                oaccT[qh][nt] = __builtin_amdgcn_mfma_f32_16x16x32_bf16(
                    vf1, pa[qh][1], oaccT[qh][nt], 0, 0, 0);
            }
        }
        __builtin_amdgcn_s_setprio(0);
    }

    float inv[2];
    #pragma unroll
    for (int qh = 0; qh < 2; ++qh) {
        float s = lsum[qh];
        s += __shfl_xor(s, 16);
        s += __shfl_xor(s, 32);
        inv[qh] = 1.f / s;
    }
    #pragma unroll
    for (int qh = 0; qh < 2; ++qh) {
        size_t orow = (size_t)(bq + q0 + wid * 32 + qh * 16 + fr) * DH_ + m * 64;
        #pragma unroll
        for (int nt = 0; nt < 4; ++nt) {
            us4 ob;
            #pragma unroll
            for (int r = 0; r < 4; ++r)
                ((unsigned short*)&ob)[r] = f2b(oaccT[qh][nt][r] * inv[qh]);
            *(us4*)&t[orow + nt * 16 + fq * 4] = ob;
        }
    }
}

// ---------------------------------------------------------------------------
// Fused BatchNorm (R13, kept): one block per position l, z = a+b cached in
// registers; stats use the EXACT reduce order of the old split version.
// 48 MB/pair vs 80 MB.
__global__ __launch_bounds__(256) void bn_fused_kernel(
    const unsigned short* __restrict__ a, const unsigned short* __restrict__ b,
    const float* __restrict__ w, const float* __restrict__ bias,
    unsigned short* __restrict__ outb, float* __restrict__ outf)
{
    int l = blockIdx.x, tid = threadIdx.x;
    us8 za[4], zb[4];
    size_t offs[4];
    float s = 0.f, s2 = 0.f;
    #pragma unroll
    for (int i = 0; i < 4; ++i) {
        int u = tid + i * 256;
        int bb = u >> 6, dg = (u & 63) * 8;
        size_t off = ((size_t)bb * L_ + l) * DH_ + dg;
        offs[i] = off;
        za[i] = *(const us8*)&a[off];
        zb[i] = *(const us8*)&b[off];
        #pragma unroll
        for (int jj = 0; jj < 8; ++jj) {
            float z = b2f(za[i][jj]) + b2f(zb[i][jj]);
            s += z;
            s2 = fmaf(z, z, s2);
        }
    }
    #pragma unroll
    for (int off = 32; off > 0; off >>= 1) {
        s  += __shfl_down(s, off);
        s2 += __shfl_down(s2, off);
    }
    __shared__ float red[8];
    __shared__ float mrs[2];
    int wv = tid >> 6;
    if ((tid & 63) == 0) { red[wv] = s; red[4 + wv] = s2; }
    __syncthreads();
    if (tid == 0) {
        float S  = red[0] + red[1] + red[2] + red[3];
        float S2 = red[4] + red[5] + red[6] + red[7];
        float mu  = S * (1.f / 8192.f);
        float var = S2 * (1.f / 8192.f) - mu * mu;
        mrs[0] = mu;
        mrs[1] = rsqrtf(var + 1e-5f);
    }
    __syncthreads();
    float mu = mrs[0], rs = mrs[1];
    #pragma unroll
    for (int i = 0; i < 4; ++i) {
        int u = tid + i * 256;
        int dg = (u & 63) * 8;
        float o[8];
        #pragma unroll
        for (int jj = 0; jj < 8; ++jj) {
            float z = b2f(za[i][jj]) + b2f(zb[i][jj]);
            o[jj] = fmaf(w[dg + jj], (z - mu) * rs, bias[dg + jj]);
        }
        if (outb) {
            us8 ob;
            #pragma unroll
            for (int jj = 0; jj < 8; ++jj) ob[jj] = f2b(o[jj]);
            *(us8*)&outb[offs[i]] = ob;
        }
        if (outf) {
            float4 o0 = {o[0], o[1], o[2], o[3]};
            float4 o1 = {o[4], o[5], o[6], o[7]};
            *(float4*)&outf[offs[i]]     = o0;
            *(float4*)&outf[offs[i] + 4] = o1;
        }
    }
}

// ---------------------------------------------------------------------------
extern "C" void kernel_launch(void* const* d_in, const int* in_sizes, int n_in,
                              void* d_out, int out_size, void* d_ws, size_t ws_size,
                              hipStream_t stream)
{
    const float* x    = (const float*)d_in[0];
    const float* Wh   = (const float*)d_in[1];
    const float* bh   = (const float*)d_in[2];
    const float* Wq   = (const float*)d_in[3];
    const float* Wk   = (const float*)d_in[4];
    const float* Wv   = (const float*)d_in[5];
    const float* Wo   = (const float*)d_in[6];
    const float* wbn  = (const float*)d_in[7];
    const float* bbn  = (const float*)d_in[8];
    const float* Wff0 = (const float*)d_in[9];
    const float* bff0 = (const float*)d_in[10];
    const float* Wff1 = (const float*)d_in[11];
    const float* bff1 = (const float*)d_in[12];
    float* out = (float*)d_out;

    // Workspace (~146 MB), all activations bf16 (layout as R5-R13)
    float* st = (float*)d_ws;
    unsigned short* hb    = (unsigned short*)(st + 2048);
    unsigned short* qkkb  = hb + (size_t)BL_ * DH_;
    unsigned short* vTb   = qkkb + (size_t)BL_ * 1024;
    unsigned short* tb    = vTb + (size_t)BL_ * DH_;
    unsigned short* mhab  = tb + (size_t)BL_ * DH_;
    unsigned short* hbnb  = mhab + (size_t)BL_ * DH_;
    unsigned short* ffob  = hbnb + (size_t)BL_ * DH_;
    unsigned short* wqkvb3 = ffob + (size_t)BL_ * DH_;
    unsigned short* wob3   = wqkvb3 + QKV_T;
    unsigned short* wff0b3 = wob3 + WO_T;
    unsigned short* wff1b3 = wff0b3 + FF_T;
    unsigned short* ffmb  = qkkb;    // alias (qkkb+vTb+tb = 64MB, dead at FF)

    wprep_kernel<<<(QKV_T + WO_T + 2 * FF_T) / 1024, 256, 0, stream>>>(
        Wq, Wk, Wv, Wo, Wff0, Wff1, wqkvb3, wob3, wff0b3, wff1b3);
    embed_kernel<<<BL_ * DH_ / 4 / 256, 256, 0, stream>>>(x, Wh, bh, hb);

    // 1D grids (%8 for XCD swizzle), tile 128x128
    const int GQKV = 12 * 128;   // gx=12
    const int GWO  = 4 * 128;    // gx=4
    const int GFF0 = 16 * 128;   // gx=16
    const int GFF1 = 4 * 128;    // gx=4

    for (int n = 0; n < NL_; ++n) {
        const unsigned short* wqkvb = wqkvb3 + (size_t)n * 786432;
        const unsigned short* wob   = wob3   + (size_t)n * 262144;
        const unsigned short* wff0b = wff0b3 + (size_t)n * 1048576;
        const unsigned short* wff1b = wff1b3 + (size_t)n * 1048576;
        const float* wbn_n  = wbn  + (size_t)n * DH_;
        const float* bbn_n  = bbn  + (size_t)n * DH_;
        const float* bff0_n = bff0 + (size_t)n * DFF_;
        const float* bff1_n = bff1 + (size_t)n * DH_;
        bool last = (n == NL_ - 1);

        // qkv: q|k -> qkkb [BL][1024] (q pre-scaled), v -> vTb transposed
        gemm2w_kernel<<<GQKV, 512, 0, stream>>>(hb, wqkvb, nullptr,
            qkkb, vTb, DH_, 1024, 4, 12);
        // t = softmax(q k^T / 8) v -> tb
        attn_mfma_kernel<<<1024, 256, 0, stream>>>(qkkb, vTb, tb);
        // h_mha = t @ wob^T -> mhab
        gemm2w_kernel<<<GWO, 512, 0, stream>>>(tb, wob, nullptr,
            mhab, nullptr, DH_, DH_, 0, 4);
        // h_bn = w*BN(h + h_mha) + b -> hbnb   (fused stats+apply)
        bn_fused_kernel<<<L_, 256, 0, stream>>>(hb, mhab, wbn_n, bbn_n,
            hbnb, nullptr);
        // ff = relu(h_bn @ Wff0^T + bff0) @ Wff1^T + bff1 -> ffob
        gemm2w_kernel<<<GFF0, 512, 0, stream>>>(hbnb, wff0b, bff0_n,
            ffmb, nullptr, DH_, DFF_, 1 | 2, 16);
        gemm2w_kernel<<<GFF1, 512, 0, stream>>>(ffmb, wff1b, bff1_n,
            ffob, nullptr, DFF_, DH_, 1, 4);
        // h = w*BN(h_bn + ff) + b  (final layer -> fp32 d_out)
        bn_fused_kernel<<<L_, 256, 0, stream>>>(hbnb, ffob, wbn_n, bbn_n,
            last ? nullptr : hb, last ? out : nullptr);
    }
}